// Round 13
// baseline (273.054 us; speedup 1.0000x reference)
//
#include <hip/hip_runtime.h>
#include <hip/hip_bf16.h>

#define F_IN 128
#define HID  64
#define NCLS 19
#define BW   128          // nodes per bucket (dst >> 7)
#define NBMAX 512         // max buckets (N <= 65536); also sortA scan width
#define ACAP 3072         // edges per k_sortA block (12 KB lbuf; ~2 blocks/CU co-resident)
#define BCAP 8192         // max edges per bucket staged in LDS by k_sortB
#define BKCAP 5120        // static per-bucket capacity (mean 4096, sigma 64 -> 16-sigma safe)
#define W1STR 136         // padded LDS stride (shorts) for W1^T rows
#define W2STR 72          // padded LDS stride (shorts) for W2^T rows

typedef __bf16 bf16x8 __attribute__((ext_vector_type(8)));
typedef float  f32x4  __attribute__((ext_vector_type(4)));

// -------- adaptive loads: flags[0]=1 -> floats are fp32 (else bf16)
//          flags[1]=1 -> indices are int64 (else int32)
__device__ __forceinline__ float ldf(const void* p, long i, int fp32) {
    if (fp32) return ((const float*)p)[i];
    return __bfloat162float(((const __hip_bfloat16*)p)[i]);
}
__device__ __forceinline__ int ldi(const void* p, long i, int i64) {
    if (i64) return (int)((const long long*)p)[i];
    return ((const int*)p)[i];
}
__device__ __forceinline__ unsigned short f2bf(float f) {
    __hip_bfloat16 h = __float2bfloat16(f);   // RNE
    unsigned short r;
    __builtin_memcpy(&r, &h, 2);
    return r;
}
__device__ __forceinline__ float bflo(unsigned u) { return __uint_as_float(u << 16); }
__device__ __forceinline__ float bfhi(unsigned u) { return __uint_as_float(u & 0xffff0000u); }

__device__ __forceinline__ bf16x8 ldfrag(const unsigned short* p) {
    uint4 u = *(const uint4*)p;
    return __builtin_bit_cast(bf16x8, u);
}
__device__ __forceinline__ bf16x8 ldfrag_any(const void* p, long off, int fp32) {
    if (!fp32) return ldfrag((const unsigned short*)p + off);
    const float* f = (const float*)p + off;
    unsigned short s[8];
#pragma unroll
    for (int i = 0; i < 8; ++i) s[i] = f2bf(f[i]);
    uint4 u = make_uint4((unsigned)s[0] | ((unsigned)s[1] << 16),
                         (unsigned)s[2] | ((unsigned)s[3] << 16),
                         (unsigned)s[4] | ((unsigned)s[5] << 16),
                         (unsigned)s[6] | ((unsigned)s[7] << 16));
    return __builtin_bit_cast(bf16x8, u);
}

// ---------------- dtype sniffer + static bucket-cursor init ----------------
__global__ __launch_bounds__(512) void k_detect(const void* x, const void* ei, int* flags,
                                                int* __restrict__ bcur, int NB) {
    int t = threadIdx.x;
    for (int b = t; b < NB; b += 512) bcur[b] = b * BKCAP;
    if (t != 0) return;
    const unsigned* xw = (const unsigned*)x;
    int bf16 = 1;
    for (int i = 0; i < 16; ++i) {
        unsigned w = xw[i];
        int elo = (w >> 7) & 0xFF;
        int ehi = (w >> 23) & 0xFF;
        if (elo < 100 || elo > 140 || ehi < 100 || ehi > 140) bf16 = 0;
    }
    const unsigned* iw = (const unsigned*)ei;
    int i64 = 1; unsigned anyev = 0;
    for (int k = 0; k < 8; ++k) {
        if (iw[2 * k + 1] != 0) i64 = 0;
        anyev |= iw[2 * k];
    }
    if (anyev == 0) i64 = 0;
    flags[0] = bf16 ? 0 : 1;
    flags[1] = i64;
}

// ---------------- per-graph segment bounds from sorted batch ----------------
__global__ __launch_bounds__(256) void k_bounds(const void* __restrict__ batch, int N, int G,
                                                int* __restrict__ bounds,
                                                const int* __restrict__ flags) {
    int i64 = flags[1];
    int i = blockIdx.x * 256 + threadIdx.x;
    if (i >= N) return;
    int b = min(max(ldi(batch, i, i64), 0), G - 1);
    int p = (i == 0) ? -1 : min(max(ldi(batch, (long)i - 1, i64), 0), G - 1);
    for (int g = p + 1; g <= b; ++g) bounds[g] = i;
    if (i == N - 1)
        for (int g = b + 1; g <= G; ++g) bounds[g] = N;
}

// ---------------- sort pass A: per-chunk LDS counting sort into static bucket regions ----------------
__global__ __launch_bounds__(512) void k_sortA(const void* __restrict__ ei, int E, int nbuck,
                                               int* bcur, int* __restrict__ bkt,
                                               const int* __restrict__ flags) {
    __shared__ int lbuf[ACAP];
    __shared__ unsigned short lbkt[ACAP];   // slot -> bucket map (no binary search)
    __shared__ int lh[NBMAX];
    __shared__ int lsc[NBMAX];
    __shared__ int lcur[NBMAX];
    __shared__ int gbase[NBMAX];
    int i64 = flags[1];
    int t = threadIdx.x;                 // 0..511
    int e0 = blockIdx.x * ACAP;
    int e1 = min(E, e0 + ACAP);
    int cnt = e1 - e0;
    lh[t] = 0;
    __syncthreads();
    for (int e = e0 + t; e < e1; e += 512)
        atomicAdd(&lh[(ldi(ei, (long)E + e, i64) >> 7) & (NBMAX - 1)], 1);
    __syncthreads();
    int v = lh[t];
    lsc[t] = v;
    __syncthreads();
    for (int off = 1; off < 512; off <<= 1) {        // Hillis-Steele inclusive
        int a = (t >= off) ? lsc[t - off] : 0;
        __syncthreads();
        lsc[t] += a;
        __syncthreads();
    }
    int ex = lsc[t] - v;                 // exclusive prefix
    lsc[t] = ex;
    lcur[t] = ex;
    gbase[t] = (v && t < nbuck) ? atomicAdd(&bcur[t], v) : 0;
    __syncthreads();
    for (int e = e0 + t; e < e1; e += 512) {
        int s = ldi(ei, e, i64);
        int d = ldi(ei, (long)E + e, i64);
        int b = (d >> 7) & (NBMAX - 1);
        int r = atomicAdd(&lcur[b], 1);
        r = min(max(r, 0), ACAP - 1);
        lbuf[r] = (s << 7) | (d & (BW - 1));
        lbkt[r] = (unsigned short)b;
    }
    __syncthreads();
    // coalesced writeout: slot i -> bucket via direct map
    for (int i = t; i < cnt; i += 512) {
        int lo = lbkt[i];
        int idx = gbase[lo] + (i - lsc[lo]);
        if (idx >= lo * BKCAP && idx < (lo + 1) * BKCAP) bkt[idx] = lbuf[i];
    }
}

// ---------------- sort pass B: per-bucket LDS counting sort -> csr, cursor, deg, dinv ----------------
__global__ __launch_bounds__(256) void k_sortB(const int* __restrict__ bkt,
                                               const int* __restrict__ bcur,
                                               int N,
                                               int* __restrict__ csr,
                                               int* __restrict__ cursor,
                                               int* __restrict__ deg,
                                               float* __restrict__ dinv) {
    __shared__ int lcsr[BCAP];
    __shared__ int lh[BW], lsc[BW], lcur[BW];
    int b = blockIdx.x, t = threadIdx.x;
    int base = b * BKCAP;
    int cnt = min(max(bcur[b] - base, 0), BKCAP);
    int end = base + cnt;
    if (t < BW) lh[t] = 0;
    __syncthreads();
    for (int i = base + t; i < end; i += 256)
        atomicAdd(&lh[bkt[i] & (BW - 1)], 1);
    __syncthreads();
    if (t < BW) lsc[t] = lh[t];
    __syncthreads();
    for (int off = 1; off < BW; off <<= 1) {
        int a = (t < BW && t >= off) ? lsc[t - off] : 0;
        __syncthreads();
        if (t < BW) lsc[t] += a;
        __syncthreads();
    }
    if (t < BW) {
        int ex = lsc[t] - lh[t];
        lcur[t] = ex;
        int n = b * BW + t;
        if (n < N) {
            cursor[n] = base + ex;
            deg[n] = lh[t];
            dinv[n] = rsqrtf((float)(lh[t] + 1));   // +1 self-loop
        }
    }
    __syncthreads();
    bool fits = (cnt <= BCAP);
    for (int i = base + t; i < end; i += 256) {
        int w = bkt[i];
        int r = atomicAdd(&lcur[w & (BW - 1)], 1);
        int sv = (int)((unsigned)w >> 7);
        if (sv >= N) sv = 0;                        // poison guard
        if (fits) { r = min(max(r, 0), BCAP - 1); lcsr[r] = sv; }
        else { r = min(max(r, 0), BKCAP - 1); csr[base + r] = sv; }
    }
    __syncthreads();
    if (fits)
        for (int i = t; i < cnt; i += 256) csr[base + i] = lcsr[i];
}

// ---------------- GEMM1 (MFMA): t[i,:] = bf16(dinv[i] * (x[i,:] @ W1)) ----------------
__global__ __launch_bounds__(256) void k_gemm1(const void* __restrict__ x,
                                               const void* __restrict__ W,
                                               const float* __restrict__ dinv,
                                               unsigned short* __restrict__ t, int N,
                                               const int* __restrict__ flags) {
    __shared__ __align__(16) unsigned short wt[HID * W1STR];   // W1^T, padded
    int fp32 = flags[0];
    int tid = threadIdx.x;
    // coalesced staging: read W row-major, write LDS transposed
    for (int i = tid; i < F_IN * HID; i += 256) {
        int k = i >> 6, n = i & 63;
        wt[n * W1STR + k] = f2bf(ldf(W, i, fp32));
    }
    __syncthreads();
    int wv = tid >> 6, lane = tid & 63;
    int quad = lane >> 4, l16 = lane & 15;
    int r0 = blockIdx.x * 64 + wv * 16;
    int rowA = min(r0 + l16, N - 1);
    bf16x8 a[4];
#pragma unroll
    for (int kq = 0; kq < 4; ++kq)
        a[kq] = ldfrag_any(x, (long)rowA * F_IN + kq * 32 + quad * 8, fp32);
    float di[4];
    int rowC = r0 + quad * 4;
#pragma unroll
    for (int r = 0; r < 4; ++r) di[r] = (rowC + r < N) ? dinv[rowC + r] : 0.f;
#pragma unroll
    for (int cg = 0; cg < 4; ++cg) {
        int col = cg * 16 + l16;
        f32x4 acc = {0.f, 0.f, 0.f, 0.f};
#pragma unroll
        for (int kq = 0; kq < 4; ++kq) {
            bf16x8 b = ldfrag(wt + col * W1STR + kq * 32 + quad * 8);
            acc = __builtin_amdgcn_mfma_f32_16x16x32_bf16(a[kq], b, acc, 0, 0, 0);
        }
#pragma unroll
        for (int r = 0; r < 4; ++r) {
            int row = rowC + r;
            if (row < N) t[(size_t)row * HID + col] = f2bf(di[r] * acc[r]);
        }
    }
}

// ---------------- GEMM2 (MFMA): t2[i,:] = bf16(dinv[i] * (h[i,:] @ W2)), h bf16 ----------------
__global__ __launch_bounds__(256) void k_gemm2(const unsigned short* __restrict__ h,
                                               const void* __restrict__ W,
                                               const float* __restrict__ dinv,
                                               unsigned short* __restrict__ t, int N,
                                               const int* __restrict__ flags) {
    __shared__ __align__(16) unsigned short wt[HID * W2STR];   // W2^T, padded
    int fp32 = flags[0];
    int tid = threadIdx.x;
    // coalesced staging: read W row-major, write LDS transposed
    for (int i = tid; i < HID * HID; i += 256) {
        int k = i >> 6, n = i & 63;
        wt[n * W2STR + k] = f2bf(ldf(W, i, fp32));
    }
    __syncthreads();
    int wv = tid >> 6, lane = tid & 63;
    int quad = lane >> 4, l16 = lane & 15;
    int r0 = blockIdx.x * 64 + wv * 16;
    int rowA = min(r0 + l16, N - 1);
    bf16x8 a[2];
#pragma unroll
    for (int kq = 0; kq < 2; ++kq)
        a[kq] = ldfrag(h + (size_t)rowA * HID + kq * 32 + quad * 8);
    float di[4];
    int rowC = r0 + quad * 4;
#pragma unroll
    for (int r = 0; r < 4; ++r) di[r] = (rowC + r < N) ? dinv[rowC + r] : 0.f;
#pragma unroll
    for (int cg = 0; cg < 4; ++cg) {
        int col = cg * 16 + l16;
        f32x4 acc = {0.f, 0.f, 0.f, 0.f};
#pragma unroll
        for (int kq = 0; kq < 2; ++kq) {
            bf16x8 b = ldfrag(wt + col * W2STR + kq * 32 + quad * 8);
            acc = __builtin_amdgcn_mfma_f32_16x16x32_bf16(a[kq], b, acc, 0, 0, 0);
        }
#pragma unroll
        for (int r = 0; r < 4; ++r) {
            int row = rowC + r;
            if (row < N) t[(size_t)row * HID + col] = f2bf(di[r] * acc[r]);
        }
    }
}

// ---------------- aggregation: feature-sliced for per-XCD L2 residency ----------------
// slice = blockIdx&1 -> 64B half-rows; with round-robin blockIdx->XCD dispatch, each
// XCD touches only one 3.2 MB slice of t (fits 4 MiB L2). 16 neighbor slots/wave,
// 4 lanes per 64B line (full line utilization). Heuristic only — correctness never
// depends on the XCD mapping.
template <bool RELU>
__global__ __launch_bounds__(256) void k_agg(const unsigned short* __restrict__ t,
                                             const int* __restrict__ csr,
                                             const int* __restrict__ cursor,
                                             const int* __restrict__ deg,
                                             const float* __restrict__ dinv,
                                             const void* __restrict__ bias,
                                             unsigned short* __restrict__ out,
                                             int N, int SZ, const int* __restrict__ flags) {
    int slice = blockIdx.x & 1;
    int node = (blockIdx.x >> 1) * 4 + (threadIdx.x >> 6);
    if (node >= N) return;
    int lane = threadIdx.x & 63;
    int slot = lane >> 2;                    // neighbor slot 0..15
    int fb = slice * 32 + (lane & 3) * 8;    // feature base (8 feats/lane, 64B line per slot)
    int beg = cursor[node];
    int dg = deg[node];
    beg = min(max(beg, 0), SZ);
    int end = beg + min(max(dg, 0), SZ - beg);
    float a0 = 0.f, a1 = 0.f, a2 = 0.f, a3 = 0.f;
    float a4 = 0.f, a5 = 0.f, a6 = 0.f, a7 = 0.f;
    for (int e = beg; e < end; e += 32) {
        int i0 = e + slot, i1 = e + 16 + slot;
        int s0 = csr[i0 < end ? i0 : end - 1];
        int s1 = csr[i1 < end ? i1 : end - 1];
        s0 = ((unsigned)s0 < (unsigned)N) ? s0 : 0;
        s1 = ((unsigned)s1 < (unsigned)N) ? s1 : 0;
        uint4 v0 = *(const uint4*)(t + (size_t)s0 * HID + fb);
        uint4 v1 = *(const uint4*)(t + (size_t)s1 * HID + fb);
        if (i0 < end) {
            a0 += bflo(v0.x); a1 += bfhi(v0.x); a2 += bflo(v0.y); a3 += bfhi(v0.y);
            a4 += bflo(v0.z); a5 += bfhi(v0.z); a6 += bflo(v0.w); a7 += bfhi(v0.w);
        }
        if (i1 < end) {
            a0 += bflo(v1.x); a1 += bfhi(v1.x); a2 += bflo(v1.y); a3 += bfhi(v1.y);
            a4 += bflo(v1.z); a5 += bfhi(v1.z); a6 += bflo(v1.w); a7 += bfhi(v1.w);
        }
    }
    // combine the 16 neighbor slots (xor over lane bits 2..5)
#pragma unroll
    for (int m = 4; m <= 32; m <<= 1) {
        a0 += __shfl_xor(a0, m); a1 += __shfl_xor(a1, m);
        a2 += __shfl_xor(a2, m); a3 += __shfl_xor(a3, m);
        a4 += __shfl_xor(a4, m); a5 += __shfl_xor(a5, m);
        a6 += __shfl_xor(a6, m); a7 += __shfl_xor(a7, m);
    }
    // self-loop
    uint4 sv = *(const uint4*)(t + (size_t)node * HID + fb);
    a0 += bflo(sv.x); a1 += bfhi(sv.x); a2 += bflo(sv.y); a3 += bfhi(sv.y);
    a4 += bflo(sv.z); a5 += bfhi(sv.z); a6 += bflo(sv.w); a7 += bfhi(sv.w);
    int fp32 = flags[0];
    float di = dinv[node];
    float v0 = di * a0 + ldf(bias, fb + 0, fp32);
    float v1 = di * a1 + ldf(bias, fb + 1, fp32);
    float v2 = di * a2 + ldf(bias, fb + 2, fp32);
    float v3 = di * a3 + ldf(bias, fb + 3, fp32);
    float v4 = di * a4 + ldf(bias, fb + 4, fp32);
    float v5 = di * a5 + ldf(bias, fb + 5, fp32);
    float v6 = di * a6 + ldf(bias, fb + 6, fp32);
    float v7 = di * a7 + ldf(bias, fb + 7, fp32);
    if (RELU) {
        v0 = fmaxf(v0, 0.f); v1 = fmaxf(v1, 0.f); v2 = fmaxf(v2, 0.f); v3 = fmaxf(v3, 0.f);
        v4 = fmaxf(v4, 0.f); v5 = fmaxf(v5, 0.f); v6 = fmaxf(v6, 0.f); v7 = fmaxf(v7, 0.f);
    }
    if (slot == 0) {
        uint4 pk;
        pk.x = (unsigned)f2bf(v0) | ((unsigned)f2bf(v1) << 16);
        pk.y = (unsigned)f2bf(v2) | ((unsigned)f2bf(v3) << 16);
        pk.z = (unsigned)f2bf(v4) | ((unsigned)f2bf(v5) << 16);
        pk.w = (unsigned)f2bf(v6) | ((unsigned)f2bf(v7) << 16);
        *(uint4*)(out + (size_t)node * HID + fb) = pk;
    }
}

// ---------------- fused mean-pool + head (bounds precomputed) ----------------
__global__ __launch_bounds__(64) void k_poolout(const unsigned short* __restrict__ h2,
                                                const int* __restrict__ bounds, int N,
                                                const void* __restrict__ Wout,
                                                const void* __restrict__ bout,
                                                void* __restrict__ out,
                                                const int* __restrict__ flags) {
    __shared__ float pr[HID];
    int g = blockIdx.x;
    int start = min(max(bounds[g], 0), N);
    int endg = min(max(bounds[g + 1], start), N);
    int lane = threadIdx.x;
    int half = lane >> 5;
    int l = lane & 31;
    float s0 = 0.f, s1 = 0.f;
    for (int r = start; r < endg; r += 4) {
        int r0 = r + half;
        int r1 = r + 2 + half;
        unsigned u0 = (r0 < endg) ? *(const unsigned*)(h2 + (size_t)r0 * HID + 2 * l) : 0u;
        unsigned u1 = (r1 < endg) ? *(const unsigned*)(h2 + (size_t)r1 * HID + 2 * l) : 0u;
        s0 += bflo(u0) + bflo(u1);
        s1 += bfhi(u0) + bfhi(u1);
    }
    s0 += __shfl_xor(s0, 32);
    s1 += __shfl_xor(s1, 32);
    if (lane < 32) {
        float inv = 1.f / fmaxf((float)(endg - start), 1.f);
        pr[2 * l] = s0 * inv;
        pr[2 * l + 1] = s1 * inv;
    }
    __syncthreads();
    int fp32 = flags[0];
    if (lane < NCLS) {
        float acc = ldf(bout, lane, fp32);
#pragma unroll 4
        for (int k = 0; k < HID; ++k)
            acc += pr[k] * ldf(Wout, k * NCLS + lane, fp32);
        if (fp32) ((float*)out)[g * NCLS + lane] = acc;
        else ((__hip_bfloat16*)out)[g * NCLS + lane] = __float2bfloat16(acc);
    }
}

extern "C" void kernel_launch(void* const* d_in, const int* in_sizes, int n_in,
                              void* d_out, int out_size, void* d_ws, size_t ws_size,
                              hipStream_t stream) {
    const void* x    = d_in[0];
    const void* ei   = d_in[1];
    const void* bat  = d_in[2];
    const void* W1   = d_in[3];
    const void* b1   = d_in[4];
    const void* W2   = d_in[5];
    const void* b2   = d_in[6];
    const void* Wout = d_in[7];
    const void* bout = d_in[8];

    const int N = in_sizes[0] / F_IN;
    const int E = in_sizes[1] / 2;
    const int G = out_size / NCLS;
    const int NB = (N + BW - 1) / BW;   // < NBMAX
    const int SZ = NB * BKCAP;          // padded csr/bkt length

    char* ws = (char*)d_ws;
    size_t off = 0;
    auto carve = [&](size_t bytes) -> void* {
        void* p = ws + off;
        off = (off + bytes + 255) & ~(size_t)255;
        return p;
    };
    int*            flags  = (int*)carve(64);
    int*            deg    = (int*)carve((size_t)N * 4);
    int*            cursor = (int*)carve((size_t)N * 4);
    float*          dinv   = (float*)carve((size_t)N * 4);
    int*            bcur   = (int*)carve((size_t)NB * 4);
    int*            bounds = (int*)carve((size_t)(G + 1) * 4);
    int*            csr    = (int*)carve((size_t)SZ * 4);
    int*            bkt    = (int*)carve((size_t)SZ * 4);
    unsigned short* t      = (unsigned short*)carve((size_t)N * HID * 2);  // t1, then h2
    unsigned short* h      = (unsigned short*)carve((size_t)N * HID * 2);  // h1, then t2
    (void)ws_size; (void)n_in;

    // sniff dtypes + init static bucket cursors
    k_detect<<<1, 512, 0, stream>>>(x, ei, flags, bcur, NB);
    // per-graph segment bounds (needs flags)
    k_bounds<<<(N + 255) / 256, 256, 0, stream>>>(bat, N, G, bounds, flags);

    // CSR build
    int na = (E + ACAP - 1) / ACAP;
    k_sortA<<<na, 512, 0, stream>>>(ei, E, NB, bcur, bkt, flags);
    k_sortB<<<NB, 256, 0, stream>>>(bkt, bcur, N, csr, cursor, deg, dinv);

    int gb = (N + 63) / 64;
    int ab = 2 * ((N + 3) / 4);         // 2 feature-slices x node groups
    // layer 1
    k_gemm1<<<gb, 256, 0, stream>>>(x, W1, dinv, t, N, flags);
    k_agg<true><<<ab, 256, 0, stream>>>(t, csr, cursor, deg, dinv, b1, h, N, SZ, flags);
    // layer 2
    k_gemm2<<<gb, 256, 0, stream>>>(h, W2, dinv, t, N, flags);   // t now holds t2
    k_agg<false><<<ab, 256, 0, stream>>>(t, csr, cursor, deg, dinv, b2, h, N, SZ, flags);  // h holds h2
    // fused pool + head
    k_poolout<<<G, 64, 0, stream>>>(h, bounds, N, Wout, bout, d_out, flags);
}

// Round 14
// 246.497 us; speedup vs baseline: 1.1077x; 1.1077x over previous
//
#include <hip/hip_runtime.h>
#include <hip/hip_bf16.h>

#define F_IN 128
#define HID  64
#define NCLS 19
#define BW   128          // nodes per bucket (dst >> 7)
#define NBMAX 512         // max buckets (N <= 65536); also sortA scan width
#define ACAP 3072         // edges per k_sortA block (12 KB lbuf; ~2 blocks/CU co-resident)
#define BCAP 8192         // max edges per bucket staged in LDS by k_sortB
#define BKCAP 5120        // static per-bucket capacity (mean 4096, sigma 64 -> 16-sigma safe)
#define W1STR 136         // padded LDS stride (shorts) for W1^T rows
#define W2STR 72          // padded LDS stride (shorts) for W2^T rows

typedef __bf16 bf16x8 __attribute__((ext_vector_type(8)));
typedef float  f32x4  __attribute__((ext_vector_type(4)));

// -------- adaptive loads: flags[0]=1 -> floats are fp32 (else bf16)
//          flags[1]=1 -> indices are int64 (else int32)
__device__ __forceinline__ float ldf(const void* p, long i, int fp32) {
    if (fp32) return ((const float*)p)[i];
    return __bfloat162float(((const __hip_bfloat16*)p)[i]);
}
__device__ __forceinline__ int ldi(const void* p, long i, int i64) {
    if (i64) return (int)((const long long*)p)[i];
    return ((const int*)p)[i];
}
__device__ __forceinline__ unsigned short f2bf(float f) {
    __hip_bfloat16 h = __float2bfloat16(f);   // RNE
    unsigned short r;
    __builtin_memcpy(&r, &h, 2);
    return r;
}
__device__ __forceinline__ float bflo(unsigned u) { return __uint_as_float(u << 16); }
__device__ __forceinline__ float bfhi(unsigned u) { return __uint_as_float(u & 0xffff0000u); }

__device__ __forceinline__ bf16x8 ldfrag(const unsigned short* p) {
    uint4 u = *(const uint4*)p;
    return __builtin_bit_cast(bf16x8, u);
}
__device__ __forceinline__ bf16x8 ldfrag_any(const void* p, long off, int fp32) {
    if (!fp32) return ldfrag((const unsigned short*)p + off);
    const float* f = (const float*)p + off;
    unsigned short s[8];
#pragma unroll
    for (int i = 0; i < 8; ++i) s[i] = f2bf(f[i]);
    uint4 u = make_uint4((unsigned)s[0] | ((unsigned)s[1] << 16),
                         (unsigned)s[2] | ((unsigned)s[3] << 16),
                         (unsigned)s[4] | ((unsigned)s[5] << 16),
                         (unsigned)s[6] | ((unsigned)s[7] << 16));
    return __builtin_bit_cast(bf16x8, u);
}

// ---------------- dtype sniffer + static bucket-cursor init ----------------
__global__ __launch_bounds__(512) void k_detect(const void* x, const void* ei, int* flags,
                                                int* __restrict__ bcur, int NB) {
    int t = threadIdx.x;
    for (int b = t; b < NB; b += 512) bcur[b] = b * BKCAP;
    if (t != 0) return;
    const unsigned* xw = (const unsigned*)x;
    int bf16 = 1;
    for (int i = 0; i < 16; ++i) {
        unsigned w = xw[i];
        int elo = (w >> 7) & 0xFF;
        int ehi = (w >> 23) & 0xFF;
        if (elo < 100 || elo > 140 || ehi < 100 || ehi > 140) bf16 = 0;
    }
    const unsigned* iw = (const unsigned*)ei;
    int i64 = 1; unsigned anyev = 0;
    for (int k = 0; k < 8; ++k) {
        if (iw[2 * k + 1] != 0) i64 = 0;
        anyev |= iw[2 * k];
    }
    if (anyev == 0) i64 = 0;
    flags[0] = bf16 ? 0 : 1;
    flags[1] = i64;
}

// ---------------- per-graph segment bounds from sorted batch ----------------
__global__ __launch_bounds__(256) void k_bounds(const void* __restrict__ batch, int N, int G,
                                                int* __restrict__ bounds,
                                                const int* __restrict__ flags) {
    int i64 = flags[1];
    int i = blockIdx.x * 256 + threadIdx.x;
    if (i >= N) return;
    int b = min(max(ldi(batch, i, i64), 0), G - 1);
    int p = (i == 0) ? -1 : min(max(ldi(batch, (long)i - 1, i64), 0), G - 1);
    for (int g = p + 1; g <= b; ++g) bounds[g] = i;
    if (i == N - 1)
        for (int g = b + 1; g <= G; ++g) bounds[g] = N;
}

// ---------------- sort pass A: per-chunk LDS counting sort into static bucket regions ----------------
__global__ __launch_bounds__(512) void k_sortA(const void* __restrict__ ei, int E, int nbuck,
                                               int* bcur, int* __restrict__ bkt,
                                               const int* __restrict__ flags) {
    __shared__ int lbuf[ACAP];
    __shared__ unsigned short lbkt[ACAP];   // slot -> bucket map (no binary search)
    __shared__ int lh[NBMAX];
    __shared__ int lsc[NBMAX];
    __shared__ int lcur[NBMAX];
    __shared__ int gbase[NBMAX];
    int i64 = flags[1];
    int t = threadIdx.x;                 // 0..511
    int e0 = blockIdx.x * ACAP;
    int e1 = min(E, e0 + ACAP);
    int cnt = e1 - e0;
    lh[t] = 0;
    __syncthreads();
    for (int e = e0 + t; e < e1; e += 512)
        atomicAdd(&lh[(ldi(ei, (long)E + e, i64) >> 7) & (NBMAX - 1)], 1);
    __syncthreads();
    int v = lh[t];
    lsc[t] = v;
    __syncthreads();
    for (int off = 1; off < 512; off <<= 1) {        // Hillis-Steele inclusive
        int a = (t >= off) ? lsc[t - off] : 0;
        __syncthreads();
        lsc[t] += a;
        __syncthreads();
    }
    int ex = lsc[t] - v;                 // exclusive prefix
    lsc[t] = ex;
    lcur[t] = ex;
    gbase[t] = (v && t < nbuck) ? atomicAdd(&bcur[t], v) : 0;
    __syncthreads();
    for (int e = e0 + t; e < e1; e += 512) {
        int s = ldi(ei, e, i64);
        int d = ldi(ei, (long)E + e, i64);
        int b = (d >> 7) & (NBMAX - 1);
        int r = atomicAdd(&lcur[b], 1);
        r = min(max(r, 0), ACAP - 1);
        lbuf[r] = (s << 7) | (d & (BW - 1));
        lbkt[r] = (unsigned short)b;
    }
    __syncthreads();
    // coalesced writeout: slot i -> bucket via direct map
    for (int i = t; i < cnt; i += 512) {
        int lo = lbkt[i];
        int idx = gbase[lo] + (i - lsc[lo]);
        if (idx >= lo * BKCAP && idx < (lo + 1) * BKCAP) bkt[idx] = lbuf[i];
    }
}

// ---------------- sort pass B: per-bucket LDS counting sort -> csr, cursor, deg, dinv ----------------
__global__ __launch_bounds__(256) void k_sortB(const int* __restrict__ bkt,
                                               const int* __restrict__ bcur,
                                               int N,
                                               int* __restrict__ csr,
                                               int* __restrict__ cursor,
                                               int* __restrict__ deg,
                                               float* __restrict__ dinv) {
    __shared__ int lcsr[BCAP];
    __shared__ int lh[BW], lsc[BW], lcur[BW];
    int b = blockIdx.x, t = threadIdx.x;
    int base = b * BKCAP;
    int cnt = min(max(bcur[b] - base, 0), BKCAP);
    int end = base + cnt;
    if (t < BW) lh[t] = 0;
    __syncthreads();
    for (int i = base + t; i < end; i += 256)
        atomicAdd(&lh[bkt[i] & (BW - 1)], 1);
    __syncthreads();
    if (t < BW) lsc[t] = lh[t];
    __syncthreads();
    for (int off = 1; off < BW; off <<= 1) {
        int a = (t < BW && t >= off) ? lsc[t - off] : 0;
        __syncthreads();
        if (t < BW) lsc[t] += a;
        __syncthreads();
    }
    if (t < BW) {
        int ex = lsc[t] - lh[t];
        lcur[t] = ex;
        int n = b * BW + t;
        if (n < N) {
            cursor[n] = base + ex;
            deg[n] = lh[t];
            dinv[n] = rsqrtf((float)(lh[t] + 1));   // +1 self-loop
        }
    }
    __syncthreads();
    bool fits = (cnt <= BCAP);
    for (int i = base + t; i < end; i += 256) {
        int w = bkt[i];
        int r = atomicAdd(&lcur[w & (BW - 1)], 1);
        int sv = (int)((unsigned)w >> 7);
        if (sv >= N) sv = 0;                        // poison guard
        if (fits) { r = min(max(r, 0), BCAP - 1); lcsr[r] = sv; }
        else { r = min(max(r, 0), BKCAP - 1); csr[base + r] = sv; }
    }
    __syncthreads();
    if (fits)
        for (int i = t; i < cnt; i += 256) csr[base + i] = lcsr[i];
}

// ---------------- GEMM1 (MFMA): t[i,:] = bf16(dinv[i] * (x[i,:] @ W1)) ----------------
__global__ __launch_bounds__(256) void k_gemm1(const void* __restrict__ x,
                                               const void* __restrict__ W,
                                               const float* __restrict__ dinv,
                                               unsigned short* __restrict__ t, int N,
                                               const int* __restrict__ flags) {
    __shared__ __align__(16) unsigned short wt[HID * W1STR];   // W1^T, padded
    int fp32 = flags[0];
    int tid = threadIdx.x;
    // coalesced staging: read W row-major, write LDS transposed
    for (int i = tid; i < F_IN * HID; i += 256) {
        int k = i >> 6, n = i & 63;
        wt[n * W1STR + k] = f2bf(ldf(W, i, fp32));
    }
    __syncthreads();
    int wv = tid >> 6, lane = tid & 63;
    int quad = lane >> 4, l16 = lane & 15;
    int r0 = blockIdx.x * 64 + wv * 16;
    int rowA = min(r0 + l16, N - 1);
    bf16x8 a[4];
#pragma unroll
    for (int kq = 0; kq < 4; ++kq)
        a[kq] = ldfrag_any(x, (long)rowA * F_IN + kq * 32 + quad * 8, fp32);
    float di[4];
    int rowC = r0 + quad * 4;
#pragma unroll
    for (int r = 0; r < 4; ++r) di[r] = (rowC + r < N) ? dinv[rowC + r] : 0.f;
#pragma unroll
    for (int cg = 0; cg < 4; ++cg) {
        int col = cg * 16 + l16;
        f32x4 acc = {0.f, 0.f, 0.f, 0.f};
#pragma unroll
        for (int kq = 0; kq < 4; ++kq) {
            bf16x8 b = ldfrag(wt + col * W1STR + kq * 32 + quad * 8);
            acc = __builtin_amdgcn_mfma_f32_16x16x32_bf16(a[kq], b, acc, 0, 0, 0);
        }
#pragma unroll
        for (int r = 0; r < 4; ++r) {
            int row = rowC + r;
            if (row < N) t[(size_t)row * HID + col] = f2bf(di[r] * acc[r]);
        }
    }
}

// ---------------- GEMM2 (MFMA): t2[i,:] = bf16(dinv[i] * (h[i,:] @ W2)), h bf16 ----------------
__global__ __launch_bounds__(256) void k_gemm2(const unsigned short* __restrict__ h,
                                               const void* __restrict__ W,
                                               const float* __restrict__ dinv,
                                               unsigned short* __restrict__ t, int N,
                                               const int* __restrict__ flags) {
    __shared__ __align__(16) unsigned short wt[HID * W2STR];   // W2^T, padded
    int fp32 = flags[0];
    int tid = threadIdx.x;
    // coalesced staging: read W row-major, write LDS transposed
    for (int i = tid; i < HID * HID; i += 256) {
        int k = i >> 6, n = i & 63;
        wt[n * W2STR + k] = f2bf(ldf(W, i, fp32));
    }
    __syncthreads();
    int wv = tid >> 6, lane = tid & 63;
    int quad = lane >> 4, l16 = lane & 15;
    int r0 = blockIdx.x * 64 + wv * 16;
    int rowA = min(r0 + l16, N - 1);
    bf16x8 a[2];
#pragma unroll
    for (int kq = 0; kq < 2; ++kq)
        a[kq] = ldfrag(h + (size_t)rowA * HID + kq * 32 + quad * 8);
    float di[4];
    int rowC = r0 + quad * 4;
#pragma unroll
    for (int r = 0; r < 4; ++r) di[r] = (rowC + r < N) ? dinv[rowC + r] : 0.f;
#pragma unroll
    for (int cg = 0; cg < 4; ++cg) {
        int col = cg * 16 + l16;
        f32x4 acc = {0.f, 0.f, 0.f, 0.f};
#pragma unroll
        for (int kq = 0; kq < 2; ++kq) {
            bf16x8 b = ldfrag(wt + col * W2STR + kq * 32 + quad * 8);
            acc = __builtin_amdgcn_mfma_f32_16x16x32_bf16(a[kq], b, acc, 0, 0, 0);
        }
#pragma unroll
        for (int r = 0; r < 4; ++r) {
            int row = rowC + r;
            if (row < N) t[(size_t)row * HID + col] = f2bf(di[r] * acc[r]);
        }
    }
}

// ---------------- aggregation: one wave per node, uint4 gathers (at the fill-rate floor) ----------------
template <bool RELU>
__global__ __launch_bounds__(256) void k_agg(const unsigned short* __restrict__ t,
                                             const int* __restrict__ csr,
                                             const int* __restrict__ cursor,
                                             const int* __restrict__ deg,
                                             const float* __restrict__ dinv,
                                             const void* __restrict__ bias,
                                             unsigned short* __restrict__ out,
                                             int N, int SZ, const int* __restrict__ flags) {
    int node = blockIdx.x * 4 + (threadIdx.x >> 6);
    if (node >= N) return;
    int lane = threadIdx.x & 63;
    int g = lane >> 3;          // neighbor slot 0..7
    int l8 = (lane & 7) * 8;    // this lane's 8 features
    int beg = cursor[node];
    int dg = deg[node];
    beg = min(max(beg, 0), SZ);
    int end = beg + min(max(dg, 0), SZ - beg);
    float a0 = 0.f, a1 = 0.f, a2 = 0.f, a3 = 0.f;
    float a4 = 0.f, a5 = 0.f, a6 = 0.f, a7 = 0.f;
    for (int e = beg; e < end; e += 32) {
        int i0 = e + g, i1 = e + 8 + g, i2 = e + 16 + g, i3 = e + 24 + g;
        int s0 = csr[i0 < end ? i0 : end - 1];
        int s1 = csr[i1 < end ? i1 : end - 1];
        int s2 = csr[i2 < end ? i2 : end - 1];
        int s3 = csr[i3 < end ? i3 : end - 1];
        s0 = ((unsigned)s0 < (unsigned)N) ? s0 : 0;
        s1 = ((unsigned)s1 < (unsigned)N) ? s1 : 0;
        s2 = ((unsigned)s2 < (unsigned)N) ? s2 : 0;
        s3 = ((unsigned)s3 < (unsigned)N) ? s3 : 0;
        uint4 v0 = *(const uint4*)(t + s0 * HID + l8);
        uint4 v1 = *(const uint4*)(t + s1 * HID + l8);
        uint4 v2 = *(const uint4*)(t + s2 * HID + l8);
        uint4 v3 = *(const uint4*)(t + s3 * HID + l8);
        if (i0 < end) {
            a0 += bflo(v0.x); a1 += bfhi(v0.x); a2 += bflo(v0.y); a3 += bfhi(v0.y);
            a4 += bflo(v0.z); a5 += bfhi(v0.z); a6 += bflo(v0.w); a7 += bfhi(v0.w);
        }
        if (i1 < end) {
            a0 += bflo(v1.x); a1 += bfhi(v1.x); a2 += bflo(v1.y); a3 += bfhi(v1.y);
            a4 += bflo(v1.z); a5 += bfhi(v1.z); a6 += bflo(v1.w); a7 += bfhi(v1.w);
        }
        if (i2 < end) {
            a0 += bflo(v2.x); a1 += bfhi(v2.x); a2 += bflo(v2.y); a3 += bfhi(v2.y);
            a4 += bflo(v2.z); a5 += bfhi(v2.z); a6 += bflo(v2.w); a7 += bfhi(v2.w);
        }
        if (i3 < end) {
            a0 += bflo(v3.x); a1 += bfhi(v3.x); a2 += bflo(v3.y); a3 += bfhi(v3.y);
            a4 += bflo(v3.z); a5 += bfhi(v3.z); a6 += bflo(v3.w); a7 += bfhi(v3.w);
        }
    }
#pragma unroll
    for (int m = 8; m <= 32; m <<= 1) {
        a0 += __shfl_xor(a0, m); a1 += __shfl_xor(a1, m);
        a2 += __shfl_xor(a2, m); a3 += __shfl_xor(a3, m);
        a4 += __shfl_xor(a4, m); a5 += __shfl_xor(a5, m);
        a6 += __shfl_xor(a6, m); a7 += __shfl_xor(a7, m);
    }
    // self-loop
    uint4 sv = *(const uint4*)(t + node * HID + l8);
    a0 += bflo(sv.x); a1 += bfhi(sv.x); a2 += bflo(sv.y); a3 += bfhi(sv.y);
    a4 += bflo(sv.z); a5 += bfhi(sv.z); a6 += bflo(sv.w); a7 += bfhi(sv.w);
    int fp32 = flags[0];
    float di = dinv[node];
    float v0 = di * a0 + ldf(bias, l8 + 0, fp32);
    float v1 = di * a1 + ldf(bias, l8 + 1, fp32);
    float v2 = di * a2 + ldf(bias, l8 + 2, fp32);
    float v3 = di * a3 + ldf(bias, l8 + 3, fp32);
    float v4 = di * a4 + ldf(bias, l8 + 4, fp32);
    float v5 = di * a5 + ldf(bias, l8 + 5, fp32);
    float v6 = di * a6 + ldf(bias, l8 + 6, fp32);
    float v7 = di * a7 + ldf(bias, l8 + 7, fp32);
    if (RELU) {
        v0 = fmaxf(v0, 0.f); v1 = fmaxf(v1, 0.f); v2 = fmaxf(v2, 0.f); v3 = fmaxf(v3, 0.f);
        v4 = fmaxf(v4, 0.f); v5 = fmaxf(v5, 0.f); v6 = fmaxf(v6, 0.f); v7 = fmaxf(v7, 0.f);
    }
    if (g == 0) {
        uint4 pk;
        pk.x = (unsigned)f2bf(v0) | ((unsigned)f2bf(v1) << 16);
        pk.y = (unsigned)f2bf(v2) | ((unsigned)f2bf(v3) << 16);
        pk.z = (unsigned)f2bf(v4) | ((unsigned)f2bf(v5) << 16);
        pk.w = (unsigned)f2bf(v6) | ((unsigned)f2bf(v7) << 16);
        *(uint4*)(out + node * HID + l8) = pk;
    }
}

// ---------------- fused mean-pool + head (bounds precomputed) ----------------
__global__ __launch_bounds__(64) void k_poolout(const unsigned short* __restrict__ h2,
                                                const int* __restrict__ bounds, int N,
                                                const void* __restrict__ Wout,
                                                const void* __restrict__ bout,
                                                void* __restrict__ out,
                                                const int* __restrict__ flags) {
    __shared__ float pr[HID];
    int g = blockIdx.x;
    int start = min(max(bounds[g], 0), N);
    int endg = min(max(bounds[g + 1], start), N);
    int lane = threadIdx.x;
    int half = lane >> 5;
    int l = lane & 31;
    float s0 = 0.f, s1 = 0.f;
    for (int r = start; r < endg; r += 4) {
        int r0 = r + half;
        int r1 = r + 2 + half;
        unsigned u0 = (r0 < endg) ? *(const unsigned*)(h2 + (size_t)r0 * HID + 2 * l) : 0u;
        unsigned u1 = (r1 < endg) ? *(const unsigned*)(h2 + (size_t)r1 * HID + 2 * l) : 0u;
        s0 += bflo(u0) + bflo(u1);
        s1 += bfhi(u0) + bfhi(u1);
    }
    s0 += __shfl_xor(s0, 32);
    s1 += __shfl_xor(s1, 32);
    if (lane < 32) {
        float inv = 1.f / fmaxf((float)(endg - start), 1.f);
        pr[2 * l] = s0 * inv;
        pr[2 * l + 1] = s1 * inv;
    }
    __syncthreads();
    int fp32 = flags[0];
    if (lane < NCLS) {
        float acc = ldf(bout, lane, fp32);
#pragma unroll 4
        for (int k = 0; k < HID; ++k)
            acc += pr[k] * ldf(Wout, k * NCLS + lane, fp32);
        if (fp32) ((float*)out)[g * NCLS + lane] = acc;
        else ((__hip_bfloat16*)out)[g * NCLS + lane] = __float2bfloat16(acc);
    }
}

extern "C" void kernel_launch(void* const* d_in, const int* in_sizes, int n_in,
                              void* d_out, int out_size, void* d_ws, size_t ws_size,
                              hipStream_t stream) {
    const void* x    = d_in[0];
    const void* ei   = d_in[1];
    const void* bat  = d_in[2];
    const void* W1   = d_in[3];
    const void* b1   = d_in[4];
    const void* W2   = d_in[5];
    const void* b2   = d_in[6];
    const void* Wout = d_in[7];
    const void* bout = d_in[8];

    const int N = in_sizes[0] / F_IN;
    const int E = in_sizes[1] / 2;
    const int G = out_size / NCLS;
    const int NB = (N + BW - 1) / BW;   // < NBMAX
    const int SZ = NB * BKCAP;          // padded csr/bkt length

    char* ws = (char*)d_ws;
    size_t off = 0;
    auto carve = [&](size_t bytes) -> void* {
        void* p = ws + off;
        off = (off + bytes + 255) & ~(size_t)255;
        return p;
    };
    int*            flags  = (int*)carve(64);
    int*            deg    = (int*)carve((size_t)N * 4);
    int*            cursor = (int*)carve((size_t)N * 4);
    float*          dinv   = (float*)carve((size_t)N * 4);
    int*            bcur   = (int*)carve((size_t)NB * 4);
    int*            bounds = (int*)carve((size_t)(G + 1) * 4);
    int*            csr    = (int*)carve((size_t)SZ * 4);
    int*            bkt    = (int*)carve((size_t)SZ * 4);
    unsigned short* t      = (unsigned short*)carve((size_t)N * HID * 2);  // t1, then h2
    unsigned short* h      = (unsigned short*)carve((size_t)N * HID * 2);  // h1, then t2
    (void)ws_size; (void)n_in;

    // sniff dtypes + init static bucket cursors
    k_detect<<<1, 512, 0, stream>>>(x, ei, flags, bcur, NB);
    // per-graph segment bounds (needs flags)
    k_bounds<<<(N + 255) / 256, 256, 0, stream>>>(bat, N, G, bounds, flags);

    // CSR build
    int na = (E + ACAP - 1) / ACAP;
    k_sortA<<<na, 512, 0, stream>>>(ei, E, NB, bcur, bkt, flags);
    k_sortB<<<NB, 256, 0, stream>>>(bkt, bcur, N, csr, cursor, deg, dinv);

    int gb = (N + 63) / 64;
    int ab = (N + 3) / 4;
    // layer 1
    k_gemm1<<<gb, 256, 0, stream>>>(x, W1, dinv, t, N, flags);
    k_agg<true><<<ab, 256, 0, stream>>>(t, csr, cursor, deg, dinv, b1, h, N, SZ, flags);
    // layer 2
    k_gemm2<<<gb, 256, 0, stream>>>(h, W2, dinv, t, N, flags);   // t now holds t2
    k_agg<false><<<ab, 256, 0, stream>>>(t, csr, cursor, deg, dinv, b2, h, N, SZ, flags);  // h holds h2
    // fused pool + head
    k_poolout<<<G, 64, 0, stream>>>(h, bounds, N, Wout, bout, d_out, flags);
}